// Round 5
// baseline (384.476 us; speedup 1.0000x reference)
//
#include <hip/hip_runtime.h>

// LocalConnectivity: diamond (L1-ball radius 5) circular convolution over
// (B=64, H=512, W=512) fp32, weight per L1-distance d: w_d = d_in[1][d-1].
//
// Decomposition (exact):
//   h_a[r][j] = sum_{|b| <= 5-a} w_{a+|b|} * s[r][(j+b)&511]   (h_0 excludes b=0)
//   out[i][j] = h_0[i][j] + sum_{a=1..5} (h_a[i-a][j] + h_a[i+a][j])
//
// Ladder: R1 spills (launch_bounds cap) 217us -> R2 direct-global 67us
// (latency-bound) -> R3 LDS row-ring 42us (barrier-serialized pipes) ->
// R4 1-wave/row 8col/lane shuffle 68us (REGRESSION: 150-float live set +
// unroll renaming -> VGPR 256 + 30 MB scratch spills).
// R5: same shuffle-halo structure, HALF the per-lane state: 4 cols/lane,
// 2 waves/block each owning a 256-col half-row. acc ring 11x4=44 regs,
// prefetch ring 4 slots (distance 3 its ~1000cyc > HBM 900cyc). Halo via
// 10 __shfl/iter from lanes t+-1,t+-2; the 4 edge lanes whose halo crosses
// the wave boundary patch from 2 predicated float4 loads, prefetched in the
// same ring. Zero LDS, zero barriers. launch_bounds(128,3) caps VGPR ~168
// (live ~120: blocks renaming bloat, can't force a spill).

#define LC_H 512
#define LC_W 512
#define LC_TY 16
#define LC_NR (LC_TY + 10)  // 26 source rows per strip

__global__ __launch_bounds__(128, 3)
void LocalConnectivity_kernel(const float* __restrict__ in,
                              const float* __restrict__ wp,
                              float* __restrict__ out) {
    const int tid = threadIdx.x;      // 0..127; col-block T = tid, cols 4T..4T+3
    const int t = tid & 63;           // lane in wave
    const int w = tid >> 6;           // wave id: half-row 0 (cols 0..255) / 1 (256..511)
    const int b = blockIdx.y;         // batch
    const int r0 = blockIdx.x * LC_TY;

    const float w1 = wp[0], w2 = wp[1], w3 = wp[2], w4 = wp[3], w5 = wp[4];

    const float* __restrict__ src = in + (size_t)b * LC_H * LC_W;
    float* __restrict__ dst = out + (size_t)b * LC_H * LC_W;

    const int laneL  = (t + 63) & 63;
    const int laneL2 = (t + 62) & 63;
    const int laneR  = (t + 1) & 63;
    const int laneR2 = (t + 2) & 63;

    const bool isEdge = (t < 2) || (t > 61);
    const bool leftE  = (t < 2);
    // edge halo base col: left lanes need cols 256w-5..256w-1 (two aligned f4
    // starting at 256w-8); right lanes cols 256w+256..+260 (f4 at 256w+256).
    const int eA = leftE ? ((256 * w - 8) & (LC_W - 1))
                         : ((256 * w + 256) & (LC_W - 1));

    float rc[4][4];   // prefetch ring: main float4, row j in slot j%4
    float re[4][5];   // prefetch ring: edge-halo values (edge lanes only)

    auto load_row = [&](int j, float* c, float* e) {
        const float* rowp = src + ((r0 + j - 5) & (LC_H - 1)) * LC_W;
        const float4 f = *reinterpret_cast<const float4*>(rowp + 4 * tid);
        c[0] = f.x; c[1] = f.y; c[2] = f.z; c[3] = f.w;
        if (isEdge) {
            const float4 fa = *reinterpret_cast<const float4*>(rowp + eA);
            const float4 fb = *reinterpret_cast<const float4*>(rowp + eA + 4);
            // left lanes: cols -8..-1 -> keep -5..-1 ; right: +256..+263 -> keep +256..+260
            e[0] = leftE ? fa.w : fa.x;
            e[1] = leftE ? fb.x : fa.y;
            e[2] = leftE ? fb.y : fa.z;
            e[3] = leftE ? fb.z : fa.w;
            e[4] = leftE ? fb.w : fb.x;
        }
    };

    float acc[11][4];  // output-row ring; first touch (a=+5) is assignment

#pragma unroll
    for (int j = 0; j < 3; ++j) load_row(j, rc[j], re[j]);  // prologue

#pragma unroll
    for (int rr = 0; rr < LC_NR; ++rr) {
        // prefetch row rr+3 (slot (rr+3)%4; slots rr..rr+3 distinct mod 4)
        if (rr + 3 < LC_NR) load_row(rr + 3, rc[(rr + 3) % 4], re[(rr + 3) % 4]);

        const float* c = rc[rr % 4];
        const float* e = re[rr % 4];

        // window x[k] = source row rr, col 4*tid - 5 + k, k=0..13
        float x[14];
        x[5] = c[0]; x[6] = c[1]; x[7] = c[2]; x[8] = c[3];
        x[1] = __shfl(c[0], laneL);
        x[2] = __shfl(c[1], laneL);
        x[3] = __shfl(c[2], laneL);
        x[4] = __shfl(c[3], laneL);
        x[0] = __shfl(c[3], laneL2);
        x[9]  = __shfl(c[0], laneR);
        x[10] = __shfl(c[1], laneR);
        x[11] = __shfl(c[2], laneR);
        x[12] = __shfl(c[3], laneR);
        x[13] = __shfl(c[0], laneR2);
        // wave-boundary patches (halo from the other half-row / wraparound)
        if (t == 0) { x[0] = e[0]; x[1] = e[1]; x[2] = e[2]; x[3] = e[3]; x[4] = e[4]; }
        if (t == 1) { x[0] = e[4]; }
        if (t == 62) { x[13] = e[0]; }
        if (t == 63) { x[9] = e[0]; x[10] = e[1]; x[11] = e[2]; x[12] = e[3]; x[13] = e[4]; }

        const int r_off = rr - 5;
#pragma unroll
        for (int q = 0; q < 4; ++q) {
            const float p0 = x[5 + q];
            const float p1 = x[4 + q] + x[6 + q];
            const float p2 = x[3 + q] + x[7 + q];
            const float p3 = x[2 + q] + x[8 + q];
            const float p4 = x[1 + q] + x[9 + q];
            const float p5 = x[0 + q] + x[10 + q];
            const float h0 = w1 * p1 + w2 * p2 + w3 * p3 + w4 * p4 + w5 * p5;
            const float h1 = w1 * p0 + w2 * p1 + w3 * p2 + w4 * p3 + w5 * p4;
            const float h2 = w2 * p0 + w3 * p1 + w4 * p2 + w5 * p3;
            const float h3 = w3 * p0 + w4 * p1 + w5 * p2;
            const float h4 = w4 * p0 + w5 * p1;
            const float h5 = w5 * p0;

            // a=+5 is the first touch of output row rr -> assignment
            if (r_off + 5 >= 0 && r_off + 5 < LC_TY) acc[(r_off + 5) % 11][q] = h5;
            if (r_off - 5 >= 0 && r_off - 5 < LC_TY) acc[(r_off - 5) % 11][q] += h5;
            if (r_off + 4 >= 0 && r_off + 4 < LC_TY) acc[(r_off + 4) % 11][q] += h4;
            if (r_off - 4 >= 0 && r_off - 4 < LC_TY) acc[(r_off - 4) % 11][q] += h4;
            if (r_off + 3 >= 0 && r_off + 3 < LC_TY) acc[(r_off + 3) % 11][q] += h3;
            if (r_off - 3 >= 0 && r_off - 3 < LC_TY) acc[(r_off - 3) % 11][q] += h3;
            if (r_off + 2 >= 0 && r_off + 2 < LC_TY) acc[(r_off + 2) % 11][q] += h2;
            if (r_off - 2 >= 0 && r_off - 2 < LC_TY) acc[(r_off - 2) % 11][q] += h2;
            if (r_off + 1 >= 0 && r_off + 1 < LC_TY) acc[(r_off + 1) % 11][q] += h1;
            if (r_off - 1 >= 0 && r_off - 1 < LC_TY) acc[(r_off - 1) % 11][q] += h1;
            if (r_off >= 0 && r_off < LC_TY)         acc[r_off % 11][q]       += h0;
        }

        // output row oc = rr - 10 is complete
        const int oc = rr - 10;
        if (oc >= 0 && oc < LC_TY) {
            const int slot = oc % 11;
            float4 f;
            f.x = acc[slot][0]; f.y = acc[slot][1];
            f.z = acc[slot][2]; f.w = acc[slot][3];
            *reinterpret_cast<float4*>(dst + (r0 + oc) * LC_W + 4 * tid) = f;
        }
    }
}

extern "C" void kernel_launch(void* const* d_in, const int* in_sizes, int n_in,
                              void* d_out, int out_size, void* d_ws, size_t ws_size,
                              hipStream_t stream) {
    const float* grid_spikes = (const float*)d_in[0];       // 64*512*512 fp32
    const float* distance_weights = (const float*)d_in[1];  // 5 fp32
    float* out = (float*)d_out;

    dim3 grid(LC_H / LC_TY, 64);  // 32 strips x 64 batches
    dim3 block(128);              // 2 waves: half-rows
    LocalConnectivity_kernel<<<grid, block, 0, stream>>>(grid_spikes, distance_weights, out);
}